// Round 27
// baseline (24.532 us; speedup 1.0000x reference)
//
#include <hip/hip_runtime.h>
#include <hip/hip_bf16.h>

typedef __attribute__((ext_vector_type(8))) short short8;
typedef __attribute__((ext_vector_type(4))) float f32x4;

#define NQ 32      // queries
#define NM 32      // query tokens
#define NH 128     // head dim
#define ND 512     // docs
#define NN 180     // doc tokens
#define MTILES 64  // max query m-tiles
#define LSTR 136   // LDS row stride in shorts (272 B; 2-way banks = free)

#define QFRAG_BYTES (MTILES * 4 * 64 * 16)    // 256 KB frag-ordered compacted Q
#define QSTART_OFF  QFRAG_BYTES               // int[33]
#define T2_OFF      (QSTART_OFF + 33 * 4)     // int

static __device__ __forceinline__ unsigned short f2bf(float x) {
  __hip_bfloat16 h = __float2bfloat16(x);
  return __builtin_bit_cast(unsigned short, h);
}

static __device__ __forceinline__ uint4 pack8(float4 a, float4 b) {
  unsigned int x = (unsigned)f2bf(a.x) | ((unsigned)f2bf(a.y) << 16);
  unsigned int y = (unsigned)f2bf(a.z) | ((unsigned)f2bf(a.w) << 16);
  unsigned int z = (unsigned)f2bf(b.x) | ((unsigned)f2bf(b.y) << 16);
  unsigned int u = (unsigned)f2bf(b.z) | ((unsigned)f2bf(b.w) << 16);
  return make_uint4(x, y, z, u);
}

// prep: GLOBAL QUERY-TOKEN COMPACTION (R22/R24-proven, unchanged).
__global__ __launch_bounds__(256) void prep_q_compact(
    const float* __restrict__ Q, const int* __restrict__ qmask,
    unsigned short* __restrict__ Qb, int* __restrict__ qstart_g,
    int* __restrict__ t2_g) {
  __shared__ unsigned short src_tok[NQ * NM];
  __shared__ int rtot[16];
  const int tid = threadIdx.x;
  const int lane = tid & 63;
  const int wv = tid >> 6;

  int flags[4], pres[4];
  #pragma unroll
  for (int r = 0; r < 4; ++r) {
    int idx = r * 256 + tid;
    int f = qmask[idx];
    unsigned long long bal = __ballot(f != 0);
    int pre = __popcll(bal & ((1ull << lane) - 1ull));
    if (lane == 63) rtot[r * 4 + wv] = pre + (f ? 1 : 0);
    flags[r] = f;
    pres[r] = pre;
  }
  __syncthreads();
  int total = 0;
  int chunkbase[4];
  {
    int run = 0;
    #pragma unroll
    for (int r = 0; r < 4; ++r) {
      chunkbase[r] = run + ((wv >= 1) ? rtot[r * 4 + 0] : 0) +
                           ((wv >= 2) ? rtot[r * 4 + 1] : 0) +
                           ((wv >= 3) ? rtot[r * 4 + 2] : 0);
      run += rtot[r * 4 + 0] + rtot[r * 4 + 1] + rtot[r * 4 + 2] + rtot[r * 4 + 3];
    }
    total = run;
  }
  #pragma unroll
  for (int r = 0; r < 4; ++r) {
    int idx = r * 256 + tid;
    int pos = chunkbase[r] + pres[r];
    if (flags[r]) src_tok[pos] = (unsigned short)idx;
    if (blockIdx.x == 0 && (idx & 31) == 0) qstart_g[idx >> 5] = pos;
  }
  __syncthreads();
  if (blockIdx.x == 0 && tid == 0) {
    qstart_g[32] = total;
    int T = (total + 15) >> 4;
    t2_g[0] = (T + 1) >> 1;
  }
  {
    int s = blockIdx.x * 256 + tid;
    int t2 = s >> 8, ks = (s >> 6) & 3, ln = s & 63;
    int col = t2 * 16 + (ln & 15);
    int kk = ks * 32 + (ln >> 4) * 8;
    uint4 o = make_uint4(0u, 0u, 0u, 0u);
    if (col < total) {
      int tok = src_tok[col];
      const float* src = Q + tok * NH + kk;
      float4 a = *reinterpret_cast<const float4*>(src);
      float4 b = *reinterpret_cast<const float4*>(src + 4);
      o = pack8(a, b);
    }
    reinterpret_cast<uint4*>(Qb)[s] = o;
  }
}

// FUSED 2-doc pipelined kernel: 256 blocks x 512 thr; block b owns docs
// {b, b+256}. LDS: 2 doc buffers (104 KB) + 2 colmax -> 1 block/CU,
// 2 waves/SIMD, VGPR budget 256 (__launch_bounds__(512,2)).
// Schedule: map both docs (one ballot phase: waves 0-2 doc0, 4-6 doc1) ->
// stage0 -> bar -> ISSUE doc1 gather+pack into 12 static regs (T14 issue-
// early) -> compute0 -> ds_write doc1 (write-late) -> bar -> compute1 ->
// bar -> 64 threads sum both docs' colmax. Doc1's HBM gather latency hides
// under compute0: one of the two exposed stage phases disappears.
// Compute body per doc = R24-verbatim (pair-strided m-tiles, tail masks).
__global__ __launch_bounds__(512, 2) void fused_maxsim2(
    const float* __restrict__ D, const int* __restrict__ dmask,
    const unsigned short* __restrict__ Qb, const int* __restrict__ qstart_g,
    const int* __restrict__ t2_g, float* __restrict__ out) {
  __shared__ unsigned short Dlds0[192 * LSTR];   // 52224 B
  __shared__ unsigned short Dlds1[192 * LSTR];   // 52224 B
  __shared__ float colmax[2][MTILES * 16];       // 8 KB
  __shared__ unsigned short mapinv0[192], mapinv1[192];
  __shared__ int wtot[8];
  const int b = blockIdx.x;
  const int d0 = b;
  const int d1 = b + 256;
  const int tid = threadIdx.x;
  const int lane = tid & 63;
  const int w = tid >> 6;
  const float NEG = -__builtin_inff();

  // ---- map phase: both docs in one ballot round ----
  // waves 0..2 scan doc0's 192 flag slots; waves 4..6 scan doc1's.
  int flag = 0, pre = 0;
  const int sub = tid & 255;            // slot within the doc (0..255)
  const int grp = tid >> 8;             // 0 = doc0 (waves 0-3), 1 = doc1
  const int dsel = grp ? d1 : d0;
  if (sub < NN) flag = dmask[dsel * NN + sub];
  if (sub < 192) {                      // waves 0-2 and 4-6
    unsigned long long bal = __ballot(flag != 0);
    pre = __popcll(bal & ((1ull << lane) - 1ull));
    if (lane == 63) wtot[w] = pre + (flag ? 1 : 0);
  }
  __syncthreads();
  const int cnt0 = wtot[0] + wtot[1] + wtot[2];
  const int cnt1 = wtot[4] + wtot[5] + wtot[6];
  if (sub < 192 && flag) {
    int wb = grp * 4;
    int base = ((w - wb) >= 1 ? wtot[wb] : 0) + ((w - wb) >= 2 ? wtot[wb + 1] : 0);
    if (grp == 0) mapinv0[pre + base] = (unsigned short)sub;
    else          mapinv1[pre + base] = (unsigned short)sub;
  }
  __syncthreads();

  const int ntc0 = (cnt0 + 15) >> 4;
  const int ntc1 = (cnt1 + 15) >> 4;
  const int T2 = t2_g[0];
  const int rg = tid >> 5;    // stage row-in-pass (0..15)
  const int c4 = tid & 31;    // stage float4 col
  const int bl = lane & 15;
  const int bg = lane >> 4;

  // ---- stage doc0 -> Dlds0 (R23-proven coalesced row-granular) ----
  {
    const int nrows = ntc0 * 16;
    #pragma unroll 4
    for (int base = 0; base < nrows; base += 16) {
      int dr = base + rg;
      uint2 o = make_uint2(0u, 0u);
      if (dr < cnt0) {
        int sr = mapinv0[dr];
        float4 v = reinterpret_cast<const float4*>(D)[(size_t)(d0 * NN + sr) * 32 + c4];
        o.x = (unsigned)f2bf(v.x) | ((unsigned)f2bf(v.y) << 16);
        o.y = (unsigned)f2bf(v.z) | ((unsigned)f2bf(v.w) << 16);
      }
      *reinterpret_cast<uint2*>(&Dlds0[dr * LSTR + c4 * 4]) = o;
    }
  }
  __syncthreads();

  // ---- issue doc1 gather + pack into 12 static regs (loads go in flight
  //      now; their latency hides under compute0 below) ----
  const int nrows1 = ntc1 * 16;
  uint2 st1[12];
  #pragma unroll
  for (int i = 0; i < 12; ++i) {
    int base = i * 16;
    int dr = base + rg;
    uint2 o = make_uint2(0u, 0u);
    if (base < nrows1 && dr < cnt1) {
      int sr = mapinv1[dr];
      float4 v = reinterpret_cast<const float4*>(D)[(size_t)(d1 * NN + sr) * 32 + c4];
      o.x = (unsigned)f2bf(v.x) | ((unsigned)f2bf(v.y) << 16);
      o.y = (unsigned)f2bf(v.z) | ((unsigned)f2bf(v.w) << 16);
    }
    st1[i] = o;
  }

  // ---- compute doc0 (R24-verbatim body) ----
  #pragma unroll 1
  for (int tp = w; tp < T2; tp += 8) {
    const int t0 = tp * 2;
    short8 Qf0[4], Qf1[4];
    #pragma unroll
    for (int ks = 0; ks < 4; ++ks) {
      Qf0[ks] = *reinterpret_cast<const short8*>(
          reinterpret_cast<const char*>(Qb) + (((t0 * 4 + ks) << 10) + (lane << 4)));
      Qf1[ks] = *reinterpret_cast<const short8*>(
          reinterpret_cast<const char*>(Qb) + ((((t0 + 1) * 4 + ks) << 10) + (lane << 4)));
    }
    float run0 = NEG, run1 = NEG;
    #pragma unroll 2
    for (int nt = 0; nt < ntc0; ++nt) {
      short8 Da[4];
      #pragma unroll
      for (int ks = 0; ks < 4; ++ks)
        Da[ks] = *reinterpret_cast<const short8*>(
            &Dlds0[(nt * 16 + bl) * LSTR + ks * 32 + bg * 8]);
      f32x4 acc0 = {0.f, 0.f, 0.f, 0.f};
      f32x4 acc1 = acc0;
      #pragma unroll
      for (int ks = 0; ks < 4; ++ks) {
        acc0 = __builtin_amdgcn_mfma_f32_16x16x32_bf16(Da[ks], Qf0[ks], acc0, 0, 0, 0);
        acc1 = __builtin_amdgcn_mfma_f32_16x16x32_bf16(Da[ks], Qf1[ks], acc1, 0, 0, 0);
      }
      if (nt * 16 + 16 > cnt0) {
        const int rlim = cnt0 - nt * 16 - bg * 4;
        float v0 = NEG, v1 = NEG;
        #pragma unroll
        for (int j = 0; j < 4; ++j) {
          v0 = fmaxf(v0, (j < rlim) ? acc0[j] : NEG);
          v1 = fmaxf(v1, (j < rlim) ? acc1[j] : NEG);
        }
        run0 = fmaxf(run0, v0);
        run1 = fmaxf(run1, v1);
      } else {
        run0 = fmaxf(run0, fmaxf(fmaxf(acc0[0], acc0[1]), fmaxf(acc0[2], acc0[3])));
        run1 = fmaxf(run1, fmaxf(fmaxf(acc1[0], acc1[1]), fmaxf(acc1[2], acc1[3])));
      }
    }
    if (cnt0 < NN) { run0 = fmaxf(run0, 0.f); run1 = fmaxf(run1, 0.f); }
    run0 = fmaxf(run0, __shfl_xor(run0, 16));
    run0 = fmaxf(run0, __shfl_xor(run0, 32));
    run1 = fmaxf(run1, __shfl_xor(run1, 16));
    run1 = fmaxf(run1, __shfl_xor(run1, 32));
    if (lane < 16) {
      colmax[0][t0 * 16 + lane] = run0;
      colmax[0][(t0 + 1) * 16 + lane] = run1;
    }
  }

  // ---- write-late: doc1 staged payload -> Dlds1 ----
  #pragma unroll
  for (int i = 0; i < 12; ++i) {
    int base = i * 16;
    if (base < nrows1) {
      int dr = base + rg;
      *reinterpret_cast<uint2*>(&Dlds1[dr * LSTR + c4 * 4]) = st1[i];
    }
  }
  __syncthreads();

  // ---- compute doc1 ----
  #pragma unroll 1
  for (int tp = w; tp < T2; tp += 8) {
    const int t0 = tp * 2;
    short8 Qf0[4], Qf1[4];
    #pragma unroll
    for (int ks = 0; ks < 4; ++ks) {
      Qf0[ks] = *reinterpret_cast<const short8*>(
          reinterpret_cast<const char*>(Qb) + (((t0 * 4 + ks) << 10) + (lane << 4)));
      Qf1[ks] = *reinterpret_cast<const short8*>(
          reinterpret_cast<const char*>(Qb) + ((((t0 + 1) * 4 + ks) << 10) + (lane << 4)));
    }
    float run0 = NEG, run1 = NEG;
    #pragma unroll 2
    for (int nt = 0; nt < ntc1; ++nt) {
      short8 Da[4];
      #pragma unroll
      for (int ks = 0; ks < 4; ++ks)
        Da[ks] = *reinterpret_cast<const short8*>(
            &Dlds1[(nt * 16 + bl) * LSTR + ks * 32 + bg * 8]);
      f32x4 acc0 = {0.f, 0.f, 0.f, 0.f};
      f32x4 acc1 = acc0;
      #pragma unroll
      for (int ks = 0; ks < 4; ++ks) {
        acc0 = __builtin_amdgcn_mfma_f32_16x16x32_bf16(Da[ks], Qf0[ks], acc0, 0, 0, 0);
        acc1 = __builtin_amdgcn_mfma_f32_16x16x32_bf16(Da[ks], Qf1[ks], acc1, 0, 0, 0);
      }
      if (nt * 16 + 16 > cnt1) {
        const int rlim = cnt1 - nt * 16 - bg * 4;
        float v0 = NEG, v1 = NEG;
        #pragma unroll
        for (int j = 0; j < 4; ++j) {
          v0 = fmaxf(v0, (j < rlim) ? acc0[j] : NEG);
          v1 = fmaxf(v1, (j < rlim) ? acc1[j] : NEG);
        }
        run0 = fmaxf(run0, v0);
        run1 = fmaxf(run1, v1);
      } else {
        run0 = fmaxf(run0, fmaxf(fmaxf(acc0[0], acc0[1]), fmaxf(acc0[2], acc0[3])));
        run1 = fmaxf(run1, fmaxf(fmaxf(acc1[0], acc1[1]), fmaxf(acc1[2], acc1[3])));
      }
    }
    if (cnt1 < NN) { run0 = fmaxf(run0, 0.f); run1 = fmaxf(run1, 0.f); }
    run0 = fmaxf(run0, __shfl_xor(run0, 16));
    run0 = fmaxf(run0, __shfl_xor(run0, 32));
    run1 = fmaxf(run1, __shfl_xor(run1, 16));
    run1 = fmaxf(run1, __shfl_xor(run1, 32));
    if (lane < 16) {
      colmax[1][t0 * 16 + lane] = run0;
      colmax[1][(t0 + 1) * 16 + lane] = run1;
    }
  }
  __syncthreads();

  // ---- per-query sums for both docs (64 threads) ----
  if (tid < 64) {
    const int q = tid & 31;
    const int dd = tid >> 5;
    const int s0 = qstart_g[q];
    const int s1 = qstart_g[q + 1];
    float s = 0.f;
    for (int i = s0; i < s1; ++i) s += colmax[dd][i];
    out[q * ND + (dd ? d1 : d0)] = s;
  }
}

extern "C" void kernel_launch(void* const* d_in, const int* in_sizes, int n_in,
                              void* d_out, int out_size, void* d_ws, size_t ws_size,
                              hipStream_t stream) {
  const float* Q = (const float*)d_in[0];
  const float* D = (const float*)d_in[1];
  const int* qmask = (const int*)d_in[2];
  const int* dmask = (const int*)d_in[3];
  float* out = (float*)d_out;

  unsigned short* Qb = (unsigned short*)d_ws;
  int* qstart_g = (int*)((char*)d_ws + QSTART_OFF);
  int* t2_g = (int*)((char*)d_ws + T2_OFF);

  prep_q_compact<<<64, 256, 0, stream>>>(Q, qmask, Qb, qstart_g, t2_g);
  fused_maxsim2<<<ND / 2, 512, 0, stream>>>(D, dmask, Qb, qstart_g, t2_g, out);
}

// Round 28
// 21.635 us; speedup vs baseline: 1.1339x; 1.1339x over previous
//
#include <hip/hip_runtime.h>
#include <hip/hip_bf16.h>

typedef __attribute__((ext_vector_type(8))) short short8;
typedef __attribute__((ext_vector_type(4))) float f32x4;

#define NQ 32      // queries
#define NM 32      // query tokens
#define NH 128     // head dim
#define ND 512     // docs
#define NN 180     // doc tokens
#define NTMAX 12   // max compacted doc n-tiles (192 rows)
#define MTILES 64  // max query m-tiles
#define LSTR 136   // LDS row stride in shorts (272 B; 2-way banks = free)

#define QFRAG_BYTES (MTILES * 4 * 64 * 16)    // 256 KB frag-ordered compacted Q
#define QSTART_OFF  QFRAG_BYTES               // int[33]
#define T2_OFF      (QSTART_OFF + 33 * 4)     // int

static __device__ __forceinline__ unsigned short f2bf(float x) {
  __hip_bfloat16 h = __float2bfloat16(x);
  return __builtin_bit_cast(unsigned short, h);
}

static __device__ __forceinline__ uint4 pack8(float4 a, float4 b) {
  unsigned int x = (unsigned)f2bf(a.x) | ((unsigned)f2bf(a.y) << 16);
  unsigned int y = (unsigned)f2bf(a.z) | ((unsigned)f2bf(a.w) << 16);
  unsigned int z = (unsigned)f2bf(b.x) | ((unsigned)f2bf(b.y) << 16);
  unsigned int u = (unsigned)f2bf(b.z) | ((unsigned)f2bf(b.w) << 16);
  return make_uint4(x, y, z, u);
}

// prep: GLOBAL QUERY-TOKEN COMPACTION (R22-proven outputs). 64 blocks x 256:
// each block scans the 1024 qmask flags in 4 ballot rounds, then builds 256
// frag slots (one 16B slot per thread). Block 0 writes qstart[33] + T2.
// Laws established this session:
//  - Qf must come from this precomputed frag buffer (in-kernel gather from
//    raw Q always loses more than a launch costs: R16, R25)
//  - computed register arrays get rematerialized/sunk unless they are plain
//    loads (R2, R3, R4, R7, R16); runtime loops keep one iteration live (R5/R6)
//  - splitting D-prep from compute adds a round-trip that always loses
//    (R12, R17, R18); cross-doc pipelining loses occupancy (R27)
//  - no cooperative launch under graph capture (R20)
__global__ __launch_bounds__(256) void prep_q_compact(
    const float* __restrict__ Q, const int* __restrict__ qmask,
    unsigned short* __restrict__ Qb, int* __restrict__ qstart_g,
    int* __restrict__ t2_g) {
  __shared__ unsigned short src_tok[NQ * NM];
  __shared__ int rtot[16];   // per (round, wave) counts: [r*4 + wv]
  const int tid = threadIdx.x;
  const int lane = tid & 63;
  const int wv = tid >> 6;

  // ---- scan 1024 flags: 4 rounds x 256 threads ----
  int flags[4], pres[4];
  #pragma unroll
  for (int r = 0; r < 4; ++r) {
    int idx = r * 256 + tid;
    int f = qmask[idx];
    unsigned long long bal = __ballot(f != 0);
    int pre = __popcll(bal & ((1ull << lane) - 1ull));
    if (lane == 63) rtot[r * 4 + wv] = pre + (f ? 1 : 0);
    flags[r] = f;
    pres[r] = pre;
  }
  __syncthreads();
  int total = 0;
  int chunkbase[4];
  {
    int run = 0;
    #pragma unroll
    for (int r = 0; r < 4; ++r) {
      chunkbase[r] = run + ((wv >= 1) ? rtot[r * 4 + 0] : 0) +
                           ((wv >= 2) ? rtot[r * 4 + 1] : 0) +
                           ((wv >= 3) ? rtot[r * 4 + 2] : 0);
      run += rtot[r * 4 + 0] + rtot[r * 4 + 1] + rtot[r * 4 + 2] + rtot[r * 4 + 3];
    }
    total = run;
  }
  #pragma unroll
  for (int r = 0; r < 4; ++r) {
    int idx = r * 256 + tid;
    int pos = chunkbase[r] + pres[r];
    if (flags[r]) src_tok[pos] = (unsigned short)idx;
    if (blockIdx.x == 0 && (idx & 31) == 0) qstart_g[idx >> 5] = pos;
  }
  __syncthreads();
  if (blockIdx.x == 0 && tid == 0) {
    qstart_g[32] = total;
    int T = (total + 15) >> 4;
    t2_g[0] = (T + 1) >> 1;
  }

  // ---- frag build: one 16B slot per thread ----
  {
    int s = blockIdx.x * 256 + tid;        // 16384 slots = 64 tiles
    int t2 = s >> 8, ks = (s >> 6) & 3, ln = s & 63;
    int col = t2 * 16 + (ln & 15);
    int kk = ks * 32 + (ln >> 4) * 8;
    uint4 o = make_uint4(0u, 0u, 0u, 0u);
    if (col < total) {
      int tok = src_tok[col];              // qmask==1 -> no multiply
      const float* src = Q + tok * NH + kk;
      float4 a = *reinterpret_cast<const float4*>(src);
      float4 b = *reinterpret_cast<const float4*>(src + 4);
      o = pack8(a, b);
    }
    reinterpret_cast<uint4*>(Qb)[s] = o;
  }
}

// FUSED per-doc kernel (verified best, 21.6 us): 512 blocks x 512 thr
// (8 waves), 2 blocks/CU, 4 waves/SIMD.
//  1) doc compaction map (ballot prefix-scan)
//  2) coalesced row-granular stage: 32 threads/doc row, mapinv broadcast,
//     row-major LDS (conflict-free writes; 2-way-free b128 reads)
//  3) m-tile PAIRS strided over waves; first pair's Qf prefetched pre-stage
//  4) colmax LDS + per-query contiguous-range sum
__global__ __launch_bounds__(512, 4) void fused_maxsim(
    const float* __restrict__ D, const int* __restrict__ dmask,
    const unsigned short* __restrict__ Qb, const int* __restrict__ qstart_g,
    const int* __restrict__ t2_g, float* __restrict__ out) {
  __shared__ unsigned short Dlds[192 * LSTR];    // 52224 B row-major bf16
  __shared__ float colmax[MTILES * 16];          // 4 KB
  __shared__ unsigned short mapinv[192];
  __shared__ int wtot[4];
  const int d = blockIdx.x;
  const int tid = threadIdx.x;
  const int lane = tid & 63;
  const int w = tid >> 6;
  const float NEG = -__builtin_inff();

  // ---- 1) doc compaction map ----
  int flag = 0, pre = 0;
  if (tid < NN) flag = dmask[d * NN + tid];
  if (tid < 192) {   // waves 0..2
    unsigned long long bal = __ballot(flag != 0);
    pre = __popcll(bal & ((1ull << lane) - 1ull));
    if (lane == 63) wtot[w] = pre + (flag ? 1 : 0);
  }
  __syncthreads();
  const int cnt = wtot[0] + wtot[1] + wtot[2];
  if (tid < 192 && flag) {
    int base = (w >= 1 ? wtot[0] : 0) + (w >= 2 ? wtot[1] : 0);
    mapinv[pre + base] = (unsigned short)tid;
  }
  __syncthreads();

  const int T2 = t2_g[0];

  // ---- Qf prefetch for this wave's FIRST m-tile pair ----
  short8 Qp0[4], Qp1[4];
  {
    const int t0 = w * 2;
    #pragma unroll
    for (int ks = 0; ks < 4; ++ks) {
      Qp0[ks] = *reinterpret_cast<const short8*>(
          reinterpret_cast<const char*>(Qb) +
          (((t0 * 4 + ks) << 10) + (lane << 4)));
      Qp1[ks] = *reinterpret_cast<const short8*>(
          reinterpret_cast<const char*>(Qb) +
          ((((t0 + 1) * 4 + ks) << 10) + (lane << 4)));
    }
  }

  // ---- 2) coalesced row-granular stage ----
  const int ntc = (cnt + 15) >> 4;
  {
    const int rg = tid >> 5;    // row-in-pass (0..15)
    const int c4 = tid & 31;    // float4 col within row
    const int nrows = ntc * 16;
    #pragma unroll 4
    for (int base = 0; base < nrows; base += 16) {
      int dr = base + rg;
      uint2 o = make_uint2(0u, 0u);
      if (dr < cnt) {
        int sr = mapinv[dr];    // broadcast across the 32-lane group
        float4 v = reinterpret_cast<const float4*>(D)[(size_t)(d * NN + sr) * 32 + c4];
        o.x = (unsigned)f2bf(v.x) | ((unsigned)f2bf(v.y) << 16);
        o.y = (unsigned)f2bf(v.z) | ((unsigned)f2bf(v.w) << 16);
      }
      *reinterpret_cast<uint2*>(&Dlds[dr * LSTR + c4 * 4]) = o;
    }
  }
  __syncthreads();

  // ---- 3) compute: m-tile pairs strided over waves ----
  const int bl = lane & 15;
  const int bg = lane >> 4;

  #pragma unroll 1
  for (int tp = w; tp < T2; tp += 8) {
    const int t0 = tp * 2;

    short8 Qf0[4], Qf1[4];
    if (tp == w) {
      #pragma unroll
      for (int ks = 0; ks < 4; ++ks) { Qf0[ks] = Qp0[ks]; Qf1[ks] = Qp1[ks]; }
    } else {
      #pragma unroll
      for (int ks = 0; ks < 4; ++ks) {
        Qf0[ks] = *reinterpret_cast<const short8*>(
            reinterpret_cast<const char*>(Qb) +
            (((t0 * 4 + ks) << 10) + (lane << 4)));
        Qf1[ks] = *reinterpret_cast<const short8*>(
            reinterpret_cast<const char*>(Qb) +
            ((((t0 + 1) * 4 + ks) << 10) + (lane << 4)));
      }
    }

    float run0 = NEG, run1 = NEG;

    #pragma unroll 2
    for (int nt = 0; nt < ntc; ++nt) {
      short8 Da[4];
      #pragma unroll
      for (int ks = 0; ks < 4; ++ks)
        Da[ks] = *reinterpret_cast<const short8*>(
            &Dlds[(nt * 16 + bl) * LSTR + ks * 32 + bg * 8]);

      f32x4 acc0 = {0.f, 0.f, 0.f, 0.f};
      f32x4 acc1 = acc0;
      #pragma unroll
      for (int ks = 0; ks < 4; ++ks) {
        acc0 = __builtin_amdgcn_mfma_f32_16x16x32_bf16(Da[ks], Qf0[ks], acc0, 0, 0, 0);
        acc1 = __builtin_amdgcn_mfma_f32_16x16x32_bf16(Da[ks], Qf1[ks], acc1, 0, 0, 0);
      }

      if (nt * 16 + 16 > cnt) {
        const int rlim = cnt - nt * 16 - bg * 4;   // lane rows: nt*16+bg*4+j
        float v0 = NEG, v1 = NEG;
        #pragma unroll
        for (int j = 0; j < 4; ++j) {
          v0 = fmaxf(v0, (j < rlim) ? acc0[j] : NEG);
          v1 = fmaxf(v1, (j < rlim) ? acc1[j] : NEG);
        }
        run0 = fmaxf(run0, v0);
        run1 = fmaxf(run1, v1);
      } else {
        run0 = fmaxf(run0, fmaxf(fmaxf(acc0[0], acc0[1]), fmaxf(acc0[2], acc0[3])));
        run1 = fmaxf(run1, fmaxf(fmaxf(acc1[0], acc1[1]), fmaxf(acc1[2], acc1[3])));
      }
    }

    // masked doc tokens inject an exact 0 into max_n
    if (cnt < NN) {
      run0 = fmaxf(run0, 0.f);
      run1 = fmaxf(run1, 0.f);
    }

    // column max across the 4 n-quarters
    run0 = fmaxf(run0, __shfl_xor(run0, 16));
    run0 = fmaxf(run0, __shfl_xor(run0, 32));
    run1 = fmaxf(run1, __shfl_xor(run1, 16));
    run1 = fmaxf(run1, __shfl_xor(run1, 32));

    if (lane < 16) {
      colmax[t0 * 16 + lane] = run0;
      colmax[(t0 + 1) * 16 + lane] = run1;
    }
  }
  __syncthreads();

  // ---- 4) per-query sum over its contiguous column range ----
  if (tid < NQ) {
    const int s0 = qstart_g[tid];
    const int s1 = qstart_g[tid + 1];
    float s = 0.f;
    for (int i = s0; i < s1; ++i) s += colmax[i];
    out[tid * ND + d] = s;
  }
}

extern "C" void kernel_launch(void* const* d_in, const int* in_sizes, int n_in,
                              void* d_out, int out_size, void* d_ws, size_t ws_size,
                              hipStream_t stream) {
  const float* Q = (const float*)d_in[0];
  const float* D = (const float*)d_in[1];
  const int* qmask = (const int*)d_in[2];
  const int* dmask = (const int*)d_in[3];
  float* out = (float*)d_out;

  unsigned short* Qb = (unsigned short*)d_ws;
  int* qstart_g = (int*)((char*)d_ws + QSTART_OFF);
  int* t2_g = (int*)((char*)d_ws + T2_OFF);

  prep_q_compact<<<64, 256, 0, stream>>>(Q, qmask, Qb, qstart_g, t2_g);
  fused_maxsim<<<ND, 512, 0, stream>>>(D, dmask, Qb, qstart_g, t2_g, out);
}